// Round 5
// baseline (925.541 us; speedup 1.0000x reference)
//
#include <hip/hip_runtime.h>
#include <cstddef>

// Problem constants (from reference setup_inputs)
static constexpr int NN   = 100000;   // nodes
static constexpr int NE   = 3200000;  // edges
static constexpr int CIN  = 512;
static constexpr int CHID = 40;
static constexpr int COUT = 20;

// ---------------- CSR build ----------------

// count in-degree AND record each edge's rank within its dst bucket.
// int4-vectorized: 4 edges/thread -> 4 independent atomics in flight.
__global__ __launch_bounds__(256) void k_count(const int* __restrict__ dst, int* __restrict__ cnt,
                                               int* __restrict__ rank, int n_edges4) {
  const int e4 = blockIdx.x * 256 + threadIdx.x;
  if (e4 >= n_edges4) return;
  const int4 d = ((const int4*)dst)[e4];
  int4 r;
  r.x = atomicAdd(&cnt[d.x], 1);
  r.y = atomicAdd(&cnt[d.y], 1);
  r.z = atomicAdd(&cnt[d.z], 1);
  r.w = atomicAdd(&cnt[d.w], 1);
  ((int4*)rank)[e4] = r;
}

// block of 256 scans 1024 elements; writes per-element exclusive scan (within block),
// block totals, and fused dinv = rsqrt(deg) = rsqrt(cnt+1).
__global__ __launch_bounds__(256) void k_scanA(const int* __restrict__ cnt, int* __restrict__ excl,
                                               int* __restrict__ bsums, float* __restrict__ dinv, int n) {
  __shared__ int sdata[256];
  const int t = threadIdx.x;
  const int base = blockIdx.x * 1024 + t * 4;
  int v[4];
#pragma unroll
  for (int j = 0; j < 4; ++j) {
    const int i = base + j;
    v[j] = (i < n) ? cnt[i] : 0;
    if (i < n) dinv[i] = rsqrtf((float)(v[j] + 1));
  }
  const int s4 = v[0] + v[1] + v[2] + v[3];
  sdata[t] = s4;
  __syncthreads();
  for (int off = 1; off < 256; off <<= 1) {
    int val = 0;
    if (t >= off) val = sdata[t - off];
    __syncthreads();
    sdata[t] += val;
    __syncthreads();
  }
  int run = sdata[t] - s4;  // exclusive prefix of this thread's 4 items
#pragma unroll
  for (int j = 0; j < 4; ++j) {
    const int i = base + j;
    if (i < n) excl[i] = run;
    run += v[j];
  }
  if (t == 255) bsums[blockIdx.x] = sdata[255];
}

__global__ __launch_bounds__(256) void k_scanB(int* __restrict__ bsums, int nb) {
  __shared__ int sdata[256];
  const int t = threadIdx.x;
  const int v = (t < nb) ? bsums[t] : 0;
  sdata[t] = v;
  __syncthreads();
  for (int off = 1; off < 256; off <<= 1) {
    int val = 0;
    if (t >= off) val = sdata[t - off];
    __syncthreads();
    sdata[t] += val;
    __syncthreads();
  }
  if (t < nb) bsums[t] = sdata[t] - v;  // exclusive, in place
}

__global__ __launch_bounds__(256) void k_scanC(int* __restrict__ rowptr, const int* __restrict__ boff,
                                               int n, int n_edges) {
  const int i = blockIdx.x * 256 + threadIdx.x;
  if (i < n) rowptr[i] += boff[i >> 10];
  if (i == 0) rowptr[n] = n_edges;
}

// pure gather + scattered 4B writes (no atomics). int4-vectorized.
__global__ __launch_bounds__(256) void k_fill(const int* __restrict__ src, const int* __restrict__ dst,
                                              const int* __restrict__ rank, const int* __restrict__ rowptr,
                                              int* __restrict__ csr_src, int n_edges4) {
  const int e4 = blockIdx.x * 256 + threadIdx.x;
  if (e4 >= n_edges4) return;
  const int4 s = ((const int4*)src)[e4];
  const int4 d = ((const int4*)dst)[e4];
  const int4 r = ((const int4*)rank)[e4];
  csr_src[rowptr[d.x] + r.x] = s.x;
  csr_src[rowptr[d.y] + r.y] = s.y;
  csr_src[rowptr[d.z] + r.z] = s.z;
  csr_src[rowptr[d.w] + r.w] = s.w;
}

// ---------------- GEMM 1: split-K x4 ----------------
// R3 profile: 187.7 us, VALUBusy 15.8%, Occupancy 17.7% -> latency-bound,
// 1563 waves (~1.5/SIMD) can't hide x-row load latency. Split K=512 into
// 4 slices of 128; block = 4 waves over the same 64 nodes (waves x4, and
// LDS 31.5KB -> 5 blocks/CU = 20 waves/CU). Waves 1-3 park partials in
// LDS (padded stride 41 = conflict-free); wave 0 reduces in registers.
// Per-channel order: ordered sum of 4 sequential quarter-sums (deterministic).

__device__ __forceinline__ void consume16(float acc[CHID], const float4 cur[4],
                                          const float* __restrict__ Wb) {
#pragma unroll
  for (int j = 0; j < 4; ++j) {
    const float4 xv = cur[j];
    const float* __restrict__ Wk = Wb + j * 4 * CHID;
#pragma unroll
    for (int c = 0; c < CHID; ++c) {
      float a = acc[c];
      a = fmaf(xv.x, Wk[c], a);
      a = fmaf(xv.y, Wk[CHID + c], a);
      a = fmaf(xv.z, Wk[2 * CHID + c], a);
      a = fmaf(xv.w, Wk[3 * CHID + c], a);
      acc[c] = a;
    }
  }
}

__global__ __launch_bounds__(256) void k_gemm1(const float* __restrict__ x, const float* __restrict__ W,
                                               float* __restrict__ h, int n) {
  __shared__ float red[3][64][41];  // 31488 B; stride 41 -> conflict-free
  const int t = threadIdx.x;
  const int nd = t & 63;
  const int ks = t >> 6;            // k-slice 0..3
  const int node = blockIdx.x * 64 + nd;

  float acc[CHID];
#pragma unroll
  for (int c = 0; c < CHID; ++c) acc[c] = 0.f;

  if (node < n) {
    const float4* __restrict__ x4 = (const float4*)(x + (size_t)node * CIN) + ks * 32;
    const float* __restrict__ Wb = W + (size_t)ks * 128 * CHID;
    float4 cur[4], nxt[4];
#pragma unroll
    for (int j = 0; j < 4; ++j) cur[j] = x4[j];
    for (int b = 0; b < 7; ++b) {  // 8 batches of 4 float4 (16 k each)
#pragma unroll
      for (int j = 0; j < 4; ++j) nxt[j] = x4[(b + 1) * 4 + j];
      consume16(acc, cur, Wb + b * 16 * CHID);
#pragma unroll
      for (int j = 0; j < 4; ++j) cur[j] = nxt[j];
    }
    consume16(acc, cur, Wb + 7 * 16 * CHID);
  }

  if (ks != 0) {
#pragma unroll
    for (int c = 0; c < CHID; ++c) red[ks - 1][nd][c] = acc[c];
  }
  __syncthreads();
  if (ks == 0 && node < n) {
#pragma unroll
    for (int c = 0; c < CHID; ++c)
      acc[c] = ((acc[c] + red[0][nd][c]) + red[1][nd][c]) + red[2][nd][c];
    float* __restrict__ o = h + (size_t)node * CHID;
#pragma unroll
    for (int c = 0; c < CHID; ++c) o[c] = acc[c];
  }
}

__global__ __launch_bounds__(256) void k_gemm2(const float* __restrict__ t1, const float* __restrict__ W,
                                               float* __restrict__ g, int n) {
  const int node = blockIdx.x * 256 + threadIdx.x;
  if (node >= n) return;
  const float4* __restrict__ r4 = (const float4*)(t1 + (size_t)node * CHID);
  float acc[COUT];
#pragma unroll
  for (int c = 0; c < COUT; ++c) acc[c] = 0.f;
#pragma unroll
  for (int kk = 0; kk < CHID / 4; ++kk) {
    const float4 xv = r4[kk];
    const float* __restrict__ Wk = W + kk * 4 * COUT;
#pragma unroll
    for (int c = 0; c < COUT; ++c) {
      float a = acc[c];
      a = fmaf(xv.x, Wk[c], a);
      a = fmaf(xv.y, Wk[COUT + c], a);
      a = fmaf(xv.z, Wk[2 * COUT + c], a);
      a = fmaf(xv.w, Wk[3 * COUT + c], a);
      acc[c] = a;
    }
  }
  float* __restrict__ o = g + (size_t)node * COUT;
#pragma unroll
  for (int c = 0; c < COUT; ++c) o[c] = acc[c];
}

// ---------------- CSR aggregation ----------------
// Layer 1 (CH=40): float2 channel-packing — 20 lanes/node, 3 nodes/wave.
__global__ __launch_bounds__(256) void k_agg40(const float* __restrict__ h, const int* __restrict__ rowptr,
                                               const int* __restrict__ csr_src, const float* __restrict__ dinv,
                                               const float* __restrict__ bias, float* __restrict__ out, int n) {
  const int wave = (blockIdx.x * 256 + (int)threadIdx.x) >> 6;
  const int lane = threadIdx.x & 63;
  const int sub  = lane / 20;   // 0..2 active; 3 => idle lanes 60..63
  const int cp   = lane % 20;   // channel pair: channels {2cp, 2cp+1}
  const int node = wave * 3 + sub;
  if (sub >= 3 || node >= n) return;
  const float2* __restrict__ h2 = (const float2*)h;
  const int r0 = rowptr[node];
  const int r1 = rowptr[node + 1];
  const float dv = dinv[node];
  const float self_w = dv * dv;  // self-loop norm = 1/deg
  float2 acc = h2[(size_t)node * 20 + cp];
  acc.x *= self_w;
  acc.y *= self_w;
  int i = r0;
  for (; i + 4 <= r1; i += 4) {
    const int s0 = csr_src[i + 0];
    const int s1 = csr_src[i + 1];
    const int s2 = csr_src[i + 2];
    const int s3 = csr_src[i + 3];
    const float w0 = dinv[s0] * dv;
    const float w1 = dinv[s1] * dv;
    const float w2 = dinv[s2] * dv;
    const float w3 = dinv[s3] * dv;
    const float2 g0 = h2[(size_t)s0 * 20 + cp];
    const float2 g1 = h2[(size_t)s1 * 20 + cp];
    const float2 g2 = h2[(size_t)s2 * 20 + cp];
    const float2 g3 = h2[(size_t)s3 * 20 + cp];
    acc.x = fmaf(g0.x, w0, acc.x); acc.y = fmaf(g0.y, w0, acc.y);
    acc.x = fmaf(g1.x, w1, acc.x); acc.y = fmaf(g1.y, w1, acc.y);
    acc.x = fmaf(g2.x, w2, acc.x); acc.y = fmaf(g2.y, w2, acc.y);
    acc.x = fmaf(g3.x, w3, acc.x); acc.y = fmaf(g3.y, w3, acc.y);
  }
  for (; i < r1; ++i) {
    const int s = csr_src[i];
    const float w = dinv[s] * dv;
    const float2 g = h2[(size_t)s * 20 + cp];
    acc.x = fmaf(g.x, w, acc.x);
    acc.y = fmaf(g.y, w, acc.y);
  }
  const float2 bv = ((const float2*)bias)[cp];
  float2 v;
  v.x = fmaxf(acc.x + bv.x, 0.f);  // ReLU (layer 1 only)
  v.y = fmaxf(acc.y + bv.y, 0.f);
  ((float2*)out)[(size_t)node * 20 + cp] = v;
}

// Layer 2 (CH=20): float2 packing — 10 lanes/node, 6 nodes/wave.
__global__ __launch_bounds__(256) void k_agg20(const float* __restrict__ h, const int* __restrict__ rowptr,
                                               const int* __restrict__ csr_src, const float* __restrict__ dinv,
                                               const float* __restrict__ bias, float* __restrict__ out, int n) {
  const int wave = (blockIdx.x * 256 + (int)threadIdx.x) >> 6;
  const int lane = threadIdx.x & 63;
  const int sub  = lane / 10;   // 0..5 active; 6 => idle lanes 60..63
  const int cp   = lane % 10;   // channel pair: channels {2cp, 2cp+1}
  const int node = wave * 6 + sub;
  if (sub >= 6 || node >= n) return;
  const float2* __restrict__ h2 = (const float2*)h;
  const int r0 = rowptr[node];
  const int r1 = rowptr[node + 1];
  const float dv = dinv[node];
  const float self_w = dv * dv;
  float2 acc = h2[(size_t)node * 10 + cp];
  acc.x *= self_w;
  acc.y *= self_w;
  int i = r0;
  for (; i + 4 <= r1; i += 4) {
    const int s0 = csr_src[i + 0];
    const int s1 = csr_src[i + 1];
    const int s2 = csr_src[i + 2];
    const int s3 = csr_src[i + 3];
    const float w0 = dinv[s0] * dv;
    const float w1 = dinv[s1] * dv;
    const float w2 = dinv[s2] * dv;
    const float w3 = dinv[s3] * dv;
    const float2 g0 = h2[(size_t)s0 * 10 + cp];
    const float2 g1 = h2[(size_t)s1 * 10 + cp];
    const float2 g2 = h2[(size_t)s2 * 10 + cp];
    const float2 g3 = h2[(size_t)s3 * 10 + cp];
    acc.x = fmaf(g0.x, w0, acc.x); acc.y = fmaf(g0.y, w0, acc.y);
    acc.x = fmaf(g1.x, w1, acc.x); acc.y = fmaf(g1.y, w1, acc.y);
    acc.x = fmaf(g2.x, w2, acc.x); acc.y = fmaf(g2.y, w2, acc.y);
    acc.x = fmaf(g3.x, w3, acc.x); acc.y = fmaf(g3.y, w3, acc.y);
  }
  for (; i < r1; ++i) {
    const int s = csr_src[i];
    const float w = dinv[s] * dv;
    const float2 g = h2[(size_t)s * 10 + cp];
    acc.x = fmaf(g.x, w, acc.x);
    acc.y = fmaf(g.y, w, acc.y);
  }
  const float2 bv = ((const float2*)bias)[cp];
  float2 v;
  v.x = acc.x + bv.x;
  v.y = acc.y + bv.y;
  ((float2*)out)[(size_t)node * 10 + cp] = v;
}

// ---------------- launch ----------------

extern "C" void kernel_launch(void* const* d_in, const int* in_sizes, int n_in,
                              void* d_out, int out_size, void* d_ws, size_t ws_size,
                              hipStream_t stream) {
  const float* x   = (const float*)d_in[0];
  const int*   ei  = (const int*)d_in[1];
  const float* W1  = (const float*)d_in[2];
  const float* b1  = (const float*)d_in[3];
  const float* W2  = (const float*)d_in[4];
  const float* b2  = (const float*)d_in[5];
  float* out = (float*)d_out;

  const int* srcp = ei;        // edge_index[0]
  const int* dstp = ei + NE;   // edge_index[1]

  // workspace layout (~59 MB)
  char* ws = (char*)d_ws;
  size_t off = 0;
  auto take = [&](size_t bytes) -> char* {
    char* p = ws + off;
    off = (off + bytes + 255) & ~(size_t)255;
    return p;
  };
  int*   cnt     = (int*)take((size_t)NN * 4);
  int*   rowptr  = (int*)take((size_t)(NN + 1) * 4);
  float* dinv    = (float*)take((size_t)NN * 4);
  int*   bsums   = (int*)take(256 * 4);
  int*   rank    = (int*)take((size_t)NE * 4);
  int*   csr_src = (int*)take((size_t)NE * 4);
  float* h1      = (float*)take((size_t)NN * CHID * 4);
  float* t1      = (float*)take((size_t)NN * CHID * 4);
  float* g2      = h1;  // h1 dead after agg1; reuse for layer-2 GEMM output

  (void)in_sizes; (void)n_in; (void)out_size; (void)ws_size;

  hipMemsetAsync(cnt, 0, (size_t)NN * 4, stream);

  const int ne4 = NE / 4;  // 800000
  k_count<<<(ne4 + 255) / 256, 256, 0, stream>>>(dstp, cnt, rank, ne4);
  const int nb = (NN + 1023) / 1024;  // 98
  k_scanA<<<nb, 256, 0, stream>>>(cnt, rowptr, bsums, dinv, NN);
  k_scanB<<<1, 256, 0, stream>>>(bsums, nb);
  k_scanC<<<(NN + 255) / 256, 256, 0, stream>>>(rowptr, bsums, NN, NE);
  k_fill<<<(ne4 + 255) / 256, 256, 0, stream>>>(srcp, dstp, rank, rowptr, csr_src, ne4);

  k_gemm1<<<(NN + 63) / 64, 256, 0, stream>>>(x, W1, h1, NN);
  const int nwaves1 = (NN + 2) / 3;            // 3 nodes per wave
  k_agg40<<<(nwaves1 + 3) / 4, 256, 0, stream>>>(h1, rowptr, csr_src, dinv, b1, t1, NN);
  k_gemm2<<<(NN + 255) / 256, 256, 0, stream>>>(t1, W2, g2, NN);
  const int nwaves2 = (NN + 5) / 6;            // 6 nodes per wave
  k_agg20<<<(nwaves2 + 3) / 4, 256, 0, stream>>>(g2, rowptr, csr_src, dinv, b2, out, NN);
}

// Round 6
// 835.830 us; speedup vs baseline: 1.1073x; 1.1073x over previous
//
#include <hip/hip_runtime.h>
#include <cstddef>

// Problem constants (from reference setup_inputs)
static constexpr int NN   = 100000;   // nodes
static constexpr int NE   = 3200000;  // edges
static constexpr int CIN  = 512;
static constexpr int CHID = 40;
static constexpr int COUT = 20;

// ---------------- CSR build ----------------

// count in-degree AND record each edge's rank within its dst bucket.
// int4-vectorized: 4 edges/thread -> 4 independent atomics in flight.
__global__ __launch_bounds__(256) void k_count(const int* __restrict__ dst, int* __restrict__ cnt,
                                               int* __restrict__ rank, int n_edges4) {
  const int e4 = blockIdx.x * 256 + threadIdx.x;
  if (e4 >= n_edges4) return;
  const int4 d = ((const int4*)dst)[e4];
  int4 r;
  r.x = atomicAdd(&cnt[d.x], 1);
  r.y = atomicAdd(&cnt[d.y], 1);
  r.z = atomicAdd(&cnt[d.z], 1);
  r.w = atomicAdd(&cnt[d.w], 1);
  ((int4*)rank)[e4] = r;
}

// block of 256 scans 1024 elements; writes per-element exclusive scan (within block),
// block totals, and fused dinv = rsqrt(deg) = rsqrt(cnt+1).
__global__ __launch_bounds__(256) void k_scanA(const int* __restrict__ cnt, int* __restrict__ excl,
                                               int* __restrict__ bsums, float* __restrict__ dinv, int n) {
  __shared__ int sdata[256];
  const int t = threadIdx.x;
  const int base = blockIdx.x * 1024 + t * 4;
  int v[4];
#pragma unroll
  for (int j = 0; j < 4; ++j) {
    const int i = base + j;
    v[j] = (i < n) ? cnt[i] : 0;
    if (i < n) dinv[i] = rsqrtf((float)(v[j] + 1));
  }
  const int s4 = v[0] + v[1] + v[2] + v[3];
  sdata[t] = s4;
  __syncthreads();
  for (int off = 1; off < 256; off <<= 1) {
    int val = 0;
    if (t >= off) val = sdata[t - off];
    __syncthreads();
    sdata[t] += val;
    __syncthreads();
  }
  int run = sdata[t] - s4;  // exclusive prefix of this thread's 4 items
#pragma unroll
  for (int j = 0; j < 4; ++j) {
    const int i = base + j;
    if (i < n) excl[i] = run;
    run += v[j];
  }
  if (t == 255) bsums[blockIdx.x] = sdata[255];
}

__global__ __launch_bounds__(256) void k_scanB(int* __restrict__ bsums, int nb) {
  __shared__ int sdata[256];
  const int t = threadIdx.x;
  const int v = (t < nb) ? bsums[t] : 0;
  sdata[t] = v;
  __syncthreads();
  for (int off = 1; off < 256; off <<= 1) {
    int val = 0;
    if (t >= off) val = sdata[t - off];
    __syncthreads();
    sdata[t] += val;
    __syncthreads();
  }
  if (t < nb) bsums[t] = sdata[t] - v;  // exclusive, in place
}

__global__ __launch_bounds__(256) void k_scanC(int* __restrict__ rowptr, const int* __restrict__ boff,
                                               int n, int n_edges) {
  const int i = blockIdx.x * 256 + threadIdx.x;
  if (i < n) rowptr[i] += boff[i >> 10];
  if (i == 0) rowptr[n] = n_edges;
}

// pure gather + scattered 4B writes (no atomics). int4-vectorized.
__global__ __launch_bounds__(256) void k_fill(const int* __restrict__ src, const int* __restrict__ dst,
                                              const int* __restrict__ rank, const int* __restrict__ rowptr,
                                              int* __restrict__ csr_src, int n_edges4) {
  const int e4 = blockIdx.x * 256 + threadIdx.x;
  if (e4 >= n_edges4) return;
  const int4 s = ((const int4*)src)[e4];
  const int4 d = ((const int4*)dst)[e4];
  const int4 r = ((const int4*)rank)[e4];
  csr_src[rowptr[d.x] + r.x] = s.x;
  csr_src[rowptr[d.y] + r.y] = s.y;
  csr_src[rowptr[d.z] + r.z] = s.z;
  csr_src[rowptr[d.w] + r.w] = s.w;
}

// ---------------- GEMM 1: coalesced LDS-tiled ----------------
// R3/R5 post-mortem: one-thread-per-row => every wave load is 64-way
// address-divergent (64 distinct 2KB-strided lines per instr). VALU work
// is only ~29us (VALUBusy*dur conserved across R3/R5); the rest is VMEM
// request serialization. Split-K (R5) raised occupancy 17.7->29.2 and
// REGRESSED 187.7->330.8us: not occupancy-bound, pattern-bound.
// Fix: block = 64 nodes x 4 waves. Per K-tile of 128: stage x[64][128]
// (32KB LDS) with fully-coalesced float4 loads; XOR-swizzle rows
// (byte ^= (row&31)<<4) so b128 writes AND per-lane row reads are
// conflict-free (lane n vs n+32 share banks = 2-way = free). Wave g owns
// channels g*10..g*10+9 (g forced to SGPR -> W fetches are scalar
// broadcasts). acc[10] lives in registers across all tiles; k ascends
// strictly -> bit-identical summation order to the R3 kernel.
__global__ __launch_bounds__(256) void k_gemm1(const float* __restrict__ x, const float* __restrict__ W,
                                               float* __restrict__ h, int n) {
  __shared__ float xt[64 * 128];  // 32 KB, XOR-swizzled rows
  const int t  = threadIdx.x;
  const int nd = t & 63;                                   // node-in-tile (compute)
  const int g  = __builtin_amdgcn_readfirstlane(t >> 6);   // channel group 0..3
  const int block0 = blockIdx.x * 64;

  // staging map: idx = r*256 + t -> row = idx>>5, float4-col = idx&31
  const int sn = t >> 5;   // rows sn, sn+8, ..., sn+56
  const int c4 = t & 31;

  float acc[10];
#pragma unroll
  for (int j = 0; j < 10; ++j) acc[j] = 0.f;

  for (int kt = 0; kt < 4; ++kt) {
    // ---- issue coalesced staging loads (before barrier: overlaps other waves' compute)
    float4 v[8];
#pragma unroll
    for (int r = 0; r < 8; ++r) {
      const int row = r * 8 + sn;
      int gn = block0 + row;
      if (gn >= n) gn = n - 1;  // clamp: valid memory, store is guarded
      v[r] = ((const float4*)(x + (size_t)gn * CIN + kt * 128))[c4];
    }
    if (kt) __syncthreads();  // previous tile fully consumed
#pragma unroll
    for (int r = 0; r < 8; ++r) {
      const int row = r * 8 + sn;
      const int byte = row * 512 + ((c4 * 16) ^ ((row & 31) << 4));
      *(float4*)((char*)xt + byte) = v[r];
    }
    __syncthreads();          // tile ready

    // ---- compute: 128 k-values, 10 channels per thread
    const float* __restrict__ Wg = W + (size_t)kt * 128 * CHID + g * 10;
#pragma unroll 4
    for (int k4 = 0; k4 < 32; ++k4) {
      const int byte = nd * 512 + ((k4 * 16) ^ ((nd & 31) << 4));
      const float4 xv = *(const float4*)((const char*)xt + byte);
      const float* __restrict__ Wk = Wg + k4 * 4 * CHID;
#pragma unroll
      for (int j = 0; j < 10; ++j) acc[j] = fmaf(xv.x, Wk[j], acc[j]);
#pragma unroll
      for (int j = 0; j < 10; ++j) acc[j] = fmaf(xv.y, Wk[CHID + j], acc[j]);
#pragma unroll
      for (int j = 0; j < 10; ++j) acc[j] = fmaf(xv.z, Wk[2 * CHID + j], acc[j]);
#pragma unroll
      for (int j = 0; j < 10; ++j) acc[j] = fmaf(xv.w, Wk[3 * CHID + j], acc[j]);
    }
  }

  const int node = block0 + nd;
  if (node < n) {
    float* __restrict__ o = h + (size_t)node * CHID + g * 10;
#pragma unroll
    for (int j = 0; j < 10; ++j) o[j] = acc[j];
  }
}

__global__ __launch_bounds__(256) void k_gemm2(const float* __restrict__ t1, const float* __restrict__ W,
                                               float* __restrict__ g, int n) {
  const int node = blockIdx.x * 256 + threadIdx.x;
  if (node >= n) return;
  const float4* __restrict__ r4 = (const float4*)(t1 + (size_t)node * CHID);
  float acc[COUT];
#pragma unroll
  for (int c = 0; c < COUT; ++c) acc[c] = 0.f;
#pragma unroll
  for (int kk = 0; kk < CHID / 4; ++kk) {
    const float4 xv = r4[kk];
    const float* __restrict__ Wk = W + kk * 4 * COUT;
#pragma unroll
    for (int c = 0; c < COUT; ++c) {
      float a = acc[c];
      a = fmaf(xv.x, Wk[c], a);
      a = fmaf(xv.y, Wk[COUT + c], a);
      a = fmaf(xv.z, Wk[2 * COUT + c], a);
      a = fmaf(xv.w, Wk[3 * COUT + c], a);
      acc[c] = a;
    }
  }
  float* __restrict__ o = g + (size_t)node * COUT;
#pragma unroll
  for (int c = 0; c < COUT; ++c) o[c] = acc[c];
}

// ---------------- CSR aggregation ----------------
// Layer 1 (CH=40): float2 channel-packing — 20 lanes/node, 3 nodes/wave.
__global__ __launch_bounds__(256) void k_agg40(const float* __restrict__ h, const int* __restrict__ rowptr,
                                               const int* __restrict__ csr_src, const float* __restrict__ dinv,
                                               const float* __restrict__ bias, float* __restrict__ out, int n) {
  const int wave = (blockIdx.x * 256 + (int)threadIdx.x) >> 6;
  const int lane = threadIdx.x & 63;
  const int sub  = lane / 20;   // 0..2 active; 3 => idle lanes 60..63
  const int cp   = lane % 20;   // channel pair: channels {2cp, 2cp+1}
  const int node = wave * 3 + sub;
  if (sub >= 3 || node >= n) return;
  const float2* __restrict__ h2 = (const float2*)h;
  const int r0 = rowptr[node];
  const int r1 = rowptr[node + 1];
  const float dv = dinv[node];
  const float self_w = dv * dv;  // self-loop norm = 1/deg
  float2 acc = h2[(size_t)node * 20 + cp];
  acc.x *= self_w;
  acc.y *= self_w;
  int i = r0;
  for (; i + 4 <= r1; i += 4) {
    const int s0 = csr_src[i + 0];
    const int s1 = csr_src[i + 1];
    const int s2 = csr_src[i + 2];
    const int s3 = csr_src[i + 3];
    const float w0 = dinv[s0] * dv;
    const float w1 = dinv[s1] * dv;
    const float w2 = dinv[s2] * dv;
    const float w3 = dinv[s3] * dv;
    const float2 g0 = h2[(size_t)s0 * 20 + cp];
    const float2 g1 = h2[(size_t)s1 * 20 + cp];
    const float2 g2 = h2[(size_t)s2 * 20 + cp];
    const float2 g3 = h2[(size_t)s3 * 20 + cp];
    acc.x = fmaf(g0.x, w0, acc.x); acc.y = fmaf(g0.y, w0, acc.y);
    acc.x = fmaf(g1.x, w1, acc.x); acc.y = fmaf(g1.y, w1, acc.y);
    acc.x = fmaf(g2.x, w2, acc.x); acc.y = fmaf(g2.y, w2, acc.y);
    acc.x = fmaf(g3.x, w3, acc.x); acc.y = fmaf(g3.y, w3, acc.y);
  }
  for (; i < r1; ++i) {
    const int s = csr_src[i];
    const float w = dinv[s] * dv;
    const float2 g = h2[(size_t)s * 20 + cp];
    acc.x = fmaf(g.x, w, acc.x);
    acc.y = fmaf(g.y, w, acc.y);
  }
  const float2 bv = ((const float2*)bias)[cp];
  float2 v;
  v.x = fmaxf(acc.x + bv.x, 0.f);  // ReLU (layer 1 only)
  v.y = fmaxf(acc.y + bv.y, 0.f);
  ((float2*)out)[(size_t)node * 20 + cp] = v;
}

// Layer 2 (CH=20): float2 packing — 10 lanes/node, 6 nodes/wave.
__global__ __launch_bounds__(256) void k_agg20(const float* __restrict__ h, const int* __restrict__ rowptr,
                                               const int* __restrict__ csr_src, const float* __restrict__ dinv,
                                               const float* __restrict__ bias, float* __restrict__ out, int n) {
  const int wave = (blockIdx.x * 256 + (int)threadIdx.x) >> 6;
  const int lane = threadIdx.x & 63;
  const int sub  = lane / 10;   // 0..5 active; 6 => idle lanes 60..63
  const int cp   = lane % 10;   // channel pair: channels {2cp, 2cp+1}
  const int node = wave * 6 + sub;
  if (sub >= 6 || node >= n) return;
  const float2* __restrict__ h2 = (const float2*)h;
  const int r0 = rowptr[node];
  const int r1 = rowptr[node + 1];
  const float dv = dinv[node];
  const float self_w = dv * dv;
  float2 acc = h2[(size_t)node * 10 + cp];
  acc.x *= self_w;
  acc.y *= self_w;
  int i = r0;
  for (; i + 4 <= r1; i += 4) {
    const int s0 = csr_src[i + 0];
    const int s1 = csr_src[i + 1];
    const int s2 = csr_src[i + 2];
    const int s3 = csr_src[i + 3];
    const float w0 = dinv[s0] * dv;
    const float w1 = dinv[s1] * dv;
    const float w2 = dinv[s2] * dv;
    const float w3 = dinv[s3] * dv;
    const float2 g0 = h2[(size_t)s0 * 10 + cp];
    const float2 g1 = h2[(size_t)s1 * 10 + cp];
    const float2 g2 = h2[(size_t)s2 * 10 + cp];
    const float2 g3 = h2[(size_t)s3 * 10 + cp];
    acc.x = fmaf(g0.x, w0, acc.x); acc.y = fmaf(g0.y, w0, acc.y);
    acc.x = fmaf(g1.x, w1, acc.x); acc.y = fmaf(g1.y, w1, acc.y);
    acc.x = fmaf(g2.x, w2, acc.x); acc.y = fmaf(g2.y, w2, acc.y);
    acc.x = fmaf(g3.x, w3, acc.x); acc.y = fmaf(g3.y, w3, acc.y);
  }
  for (; i < r1; ++i) {
    const int s = csr_src[i];
    const float w = dinv[s] * dv;
    const float2 g = h2[(size_t)s * 10 + cp];
    acc.x = fmaf(g.x, w, acc.x);
    acc.y = fmaf(g.y, w, acc.y);
  }
  const float2 bv = ((const float2*)bias)[cp];
  float2 v;
  v.x = acc.x + bv.x;
  v.y = acc.y + bv.y;
  ((float2*)out)[(size_t)node * 10 + cp] = v;
}

// ---------------- launch ----------------

extern "C" void kernel_launch(void* const* d_in, const int* in_sizes, int n_in,
                              void* d_out, int out_size, void* d_ws, size_t ws_size,
                              hipStream_t stream) {
  const float* x   = (const float*)d_in[0];
  const int*   ei  = (const int*)d_in[1];
  const float* W1  = (const float*)d_in[2];
  const float* b1  = (const float*)d_in[3];
  const float* W2  = (const float*)d_in[4];
  const float* b2  = (const float*)d_in[5];
  float* out = (float*)d_out;

  const int* srcp = ei;        // edge_index[0]
  const int* dstp = ei + NE;   // edge_index[1]

  // workspace layout (~59 MB)
  char* ws = (char*)d_ws;
  size_t off = 0;
  auto take = [&](size_t bytes) -> char* {
    char* p = ws + off;
    off = (off + bytes + 255) & ~(size_t)255;
    return p;
  };
  int*   cnt     = (int*)take((size_t)NN * 4);
  int*   rowptr  = (int*)take((size_t)(NN + 1) * 4);
  float* dinv    = (float*)take((size_t)NN * 4);
  int*   bsums   = (int*)take(256 * 4);
  int*   rank    = (int*)take((size_t)NE * 4);
  int*   csr_src = (int*)take((size_t)NE * 4);
  float* h1      = (float*)take((size_t)NN * CHID * 4);
  float* t1      = (float*)take((size_t)NN * CHID * 4);
  float* g2      = h1;  // h1 dead after agg1; reuse for layer-2 GEMM output

  (void)in_sizes; (void)n_in; (void)out_size; (void)ws_size;

  hipMemsetAsync(cnt, 0, (size_t)NN * 4, stream);

  const int ne4 = NE / 4;  // 800000
  k_count<<<(ne4 + 255) / 256, 256, 0, stream>>>(dstp, cnt, rank, ne4);
  const int nb = (NN + 1023) / 1024;  // 98
  k_scanA<<<nb, 256, 0, stream>>>(cnt, rowptr, bsums, dinv, NN);
  k_scanB<<<1, 256, 0, stream>>>(bsums, nb);
  k_scanC<<<(NN + 255) / 256, 256, 0, stream>>>(rowptr, bsums, NN, NE);
  k_fill<<<(ne4 + 255) / 256, 256, 0, stream>>>(srcp, dstp, rank, rowptr, csr_src, ne4);

  k_gemm1<<<(NN + 63) / 64, 256, 0, stream>>>(x, W1, h1, NN);
  const int nwaves1 = (NN + 2) / 3;            // 3 nodes per wave
  k_agg40<<<(nwaves1 + 3) / 4, 256, 0, stream>>>(h1, rowptr, csr_src, dinv, b1, t1, NN);
  k_gemm2<<<(NN + 255) / 256, 256, 0, stream>>>(t1, W2, g2, NN);
  const int nwaves2 = (NN + 5) / 6;            // 6 nodes per wave
  k_agg20<<<(nwaves2 + 3) / 4, 256, 0, stream>>>(g2, rowptr, csr_src, dinv, b2, out, NN);
}

// Round 7
// 824.939 us; speedup vs baseline: 1.1220x; 1.0132x over previous
//
#include <hip/hip_runtime.h>
#include <cstddef>

// Problem constants (from reference setup_inputs)
static constexpr int NN   = 100000;   // nodes
static constexpr int NE   = 3200000;  // edges
static constexpr int CIN  = 512;
static constexpr int CHID = 40;
static constexpr int COUT = 20;

// ---------------- CSR build ----------------

// count in-degree AND record each edge's rank within its dst bucket.
// int4-vectorized: 4 edges/thread -> 4 independent atomics in flight.
__global__ __launch_bounds__(256) void k_count(const int* __restrict__ dst, int* __restrict__ cnt,
                                               int* __restrict__ rank, int n_edges4) {
  const int e4 = blockIdx.x * 256 + threadIdx.x;
  if (e4 >= n_edges4) return;
  const int4 d = ((const int4*)dst)[e4];
  int4 r;
  r.x = atomicAdd(&cnt[d.x], 1);
  r.y = atomicAdd(&cnt[d.y], 1);
  r.z = atomicAdd(&cnt[d.z], 1);
  r.w = atomicAdd(&cnt[d.w], 1);
  ((int4*)rank)[e4] = r;
}

// block of 256 scans 1024 elements; writes per-element exclusive scan (within block),
// block totals, and fused dinv = rsqrt(deg) = rsqrt(cnt+1).
__global__ __launch_bounds__(256) void k_scanA(const int* __restrict__ cnt, int* __restrict__ excl,
                                               int* __restrict__ bsums, float* __restrict__ dinv, int n) {
  __shared__ int sdata[256];
  const int t = threadIdx.x;
  const int base = blockIdx.x * 1024 + t * 4;
  int v[4];
#pragma unroll
  for (int j = 0; j < 4; ++j) {
    const int i = base + j;
    v[j] = (i < n) ? cnt[i] : 0;
    if (i < n) dinv[i] = rsqrtf((float)(v[j] + 1));
  }
  const int s4 = v[0] + v[1] + v[2] + v[3];
  sdata[t] = s4;
  __syncthreads();
  for (int off = 1; off < 256; off <<= 1) {
    int val = 0;
    if (t >= off) val = sdata[t - off];
    __syncthreads();
    sdata[t] += val;
    __syncthreads();
  }
  int run = sdata[t] - s4;  // exclusive prefix of this thread's 4 items
#pragma unroll
  for (int j = 0; j < 4; ++j) {
    const int i = base + j;
    if (i < n) excl[i] = run;
    run += v[j];
  }
  if (t == 255) bsums[blockIdx.x] = sdata[255];
}

__global__ __launch_bounds__(256) void k_scanB(int* __restrict__ bsums, int nb) {
  __shared__ int sdata[256];
  const int t = threadIdx.x;
  const int v = (t < nb) ? bsums[t] : 0;
  sdata[t] = v;
  __syncthreads();
  for (int off = 1; off < 256; off <<= 1) {
    int val = 0;
    if (t >= off) val = sdata[t - off];
    __syncthreads();
    sdata[t] += val;
    __syncthreads();
  }
  if (t < nb) bsums[t] = sdata[t] - v;  // exclusive, in place
}

__global__ __launch_bounds__(256) void k_scanC(int* __restrict__ rowptr, const int* __restrict__ boff,
                                               int n, int n_edges) {
  const int i = blockIdx.x * 256 + threadIdx.x;
  if (i < n) rowptr[i] += boff[i >> 10];
  if (i == 0) rowptr[n] = n_edges;
}

// pure gather + scattered 4B writes (no atomics). int4-vectorized.
__global__ __launch_bounds__(256) void k_fill(const int* __restrict__ src, const int* __restrict__ dst,
                                              const int* __restrict__ rank, const int* __restrict__ rowptr,
                                              int* __restrict__ csr_src, int n_edges4) {
  const int e4 = blockIdx.x * 256 + threadIdx.x;
  if (e4 >= n_edges4) return;
  const int4 s = ((const int4*)src)[e4];
  const int4 d = ((const int4*)dst)[e4];
  const int4 r = ((const int4*)rank)[e4];
  csr_src[rowptr[d.x] + r.x] = s.x;
  csr_src[rowptr[d.y] + r.y] = s.y;
  csr_src[rowptr[d.z] + r.z] = s.z;
  csr_src[rowptr[d.w] + r.w] = s.w;
}

// ---------------- GEMM 1: coalesced LDS-tiled, coalesced epilogue ----------------
// R6 post-mortem: staging/compute fine (HBM 365->1520 GB/s) but WRITE_SIZE
// exploded 15.6 -> 215.7 MB (13.8x): each 160B h-row was written in four
// 40B chunks by four DIFFERENT waves -> no wave covers a full line -> write
// combining fails -> sector-granular HBM writes + RMW fetches.
// Fix: park acc in LDS (xt reused, stride 44 floats = 16B-aligned), then
// stream the block's 64x160B output as 640 contiguous float4 stores --
// every 128B line covered by consecutive lanes of one wave.
// k ascends strictly -> summation order identical to R3/R6 (absmax 4.88e-4).
__global__ __launch_bounds__(256) void k_gemm1(const float* __restrict__ x, const float* __restrict__ W,
                                               float* __restrict__ h, int n) {
  __shared__ float xt[64 * 128];  // 32 KB; reused as output staging [64][44]
  const int t  = threadIdx.x;
  const int nd = t & 63;                                   // node-in-tile (compute)
  const int g  = __builtin_amdgcn_readfirstlane(t >> 6);   // channel group 0..3
  const int block0 = blockIdx.x * 64;

  // staging map: idx = r*256 + t -> row = idx>>5, float4-col = idx&31
  const int sn = t >> 5;   // rows sn, sn+8, ..., sn+56
  const int c4 = t & 31;

  float acc[10];
#pragma unroll
  for (int j = 0; j < 10; ++j) acc[j] = 0.f;

  for (int kt = 0; kt < 4; ++kt) {
    // ---- issue coalesced staging loads (before barrier: overlaps other waves' compute)
    float4 v[8];
#pragma unroll
    for (int r = 0; r < 8; ++r) {
      const int row = r * 8 + sn;
      int gn = block0 + row;
      if (gn >= n) gn = n - 1;  // clamp: valid memory, store is guarded
      v[r] = ((const float4*)(x + (size_t)gn * CIN + kt * 128))[c4];
    }
    if (kt) __syncthreads();  // previous tile fully consumed
#pragma unroll
    for (int r = 0; r < 8; ++r) {
      const int row = r * 8 + sn;
      const int byte = row * 512 + ((c4 * 16) ^ ((row & 31) << 4));
      *(float4*)((char*)xt + byte) = v[r];
    }
    __syncthreads();          // tile ready

    // ---- compute: 128 k-values, 10 channels per thread
    const float* __restrict__ Wg = W + (size_t)kt * 128 * CHID + g * 10;
#pragma unroll 4
    for (int k4 = 0; k4 < 32; ++k4) {
      const int byte = nd * 512 + ((k4 * 16) ^ ((nd & 31) << 4));
      const float4 xv = *(const float4*)((const char*)xt + byte);
      const float* __restrict__ Wk = Wg + k4 * 4 * CHID;
#pragma unroll
      for (int j = 0; j < 10; ++j) acc[j] = fmaf(xv.x, Wk[j], acc[j]);
#pragma unroll
      for (int j = 0; j < 10; ++j) acc[j] = fmaf(xv.y, Wk[CHID + j], acc[j]);
#pragma unroll
      for (int j = 0; j < 10; ++j) acc[j] = fmaf(xv.z, Wk[2 * CHID + j], acc[j]);
#pragma unroll
      for (int j = 0; j < 10; ++j) acc[j] = fmaf(xv.w, Wk[3 * CHID + j], acc[j]);
    }
  }

  // ---- coalesced epilogue through LDS ----
  __syncthreads();  // all waves done reading xt
#pragma unroll
  for (int j = 0; j < 10; ++j) xt[nd * 44 + g * 10 + j] = acc[j];
  __syncthreads();
  // 64 rows x 40 floats = 640 float4, contiguous across the block's h region
  for (int i = t; i < 640; i += 256) {
    const int row = i / 10;
    const int c   = i % 10;
    const int node = block0 + row;
    if (node < n)
      ((float4*)(h + (size_t)node * CHID))[c] = *(const float4*)&xt[row * 44 + c * 4];
  }
}

__global__ __launch_bounds__(256) void k_gemm2(const float* __restrict__ t1, const float* __restrict__ W,
                                               float* __restrict__ g, int n) {
  const int node = blockIdx.x * 256 + threadIdx.x;
  if (node >= n) return;
  const float4* __restrict__ r4 = (const float4*)(t1 + (size_t)node * CHID);
  float acc[COUT];
#pragma unroll
  for (int c = 0; c < COUT; ++c) acc[c] = 0.f;
#pragma unroll
  for (int kk = 0; kk < CHID / 4; ++kk) {
    const float4 xv = r4[kk];
    const float* __restrict__ Wk = W + kk * 4 * COUT;
#pragma unroll
    for (int c = 0; c < COUT; ++c) {
      float a = acc[c];
      a = fmaf(xv.x, Wk[c], a);
      a = fmaf(xv.y, Wk[COUT + c], a);
      a = fmaf(xv.z, Wk[2 * COUT + c], a);
      a = fmaf(xv.w, Wk[3 * COUT + c], a);
      acc[c] = a;
    }
  }
  float* __restrict__ o = g + (size_t)node * COUT;
#pragma unroll
  for (int c = 0; c < COUT; ++c) o[c] = acc[c];
}

// ---------------- CSR aggregation ----------------
// Layer 1 (CH=40): float2 channel-packing — 20 lanes/node, 3 nodes/wave.
__global__ __launch_bounds__(256) void k_agg40(const float* __restrict__ h, const int* __restrict__ rowptr,
                                               const int* __restrict__ csr_src, const float* __restrict__ dinv,
                                               const float* __restrict__ bias, float* __restrict__ out, int n) {
  const int wave = (blockIdx.x * 256 + (int)threadIdx.x) >> 6;
  const int lane = threadIdx.x & 63;
  const int sub  = lane / 20;   // 0..2 active; 3 => idle lanes 60..63
  const int cp   = lane % 20;   // channel pair: channels {2cp, 2cp+1}
  const int node = wave * 3 + sub;
  if (sub >= 3 || node >= n) return;
  const float2* __restrict__ h2 = (const float2*)h;
  const int r0 = rowptr[node];
  const int r1 = rowptr[node + 1];
  const float dv = dinv[node];
  const float self_w = dv * dv;  // self-loop norm = 1/deg
  float2 acc = h2[(size_t)node * 20 + cp];
  acc.x *= self_w;
  acc.y *= self_w;
  int i = r0;
  for (; i + 4 <= r1; i += 4) {
    const int s0 = csr_src[i + 0];
    const int s1 = csr_src[i + 1];
    const int s2 = csr_src[i + 2];
    const int s3 = csr_src[i + 3];
    const float w0 = dinv[s0] * dv;
    const float w1 = dinv[s1] * dv;
    const float w2 = dinv[s2] * dv;
    const float w3 = dinv[s3] * dv;
    const float2 g0 = h2[(size_t)s0 * 20 + cp];
    const float2 g1 = h2[(size_t)s1 * 20 + cp];
    const float2 g2 = h2[(size_t)s2 * 20 + cp];
    const float2 g3 = h2[(size_t)s3 * 20 + cp];
    acc.x = fmaf(g0.x, w0, acc.x); acc.y = fmaf(g0.y, w0, acc.y);
    acc.x = fmaf(g1.x, w1, acc.x); acc.y = fmaf(g1.y, w1, acc.y);
    acc.x = fmaf(g2.x, w2, acc.x); acc.y = fmaf(g2.y, w2, acc.y);
    acc.x = fmaf(g3.x, w3, acc.x); acc.y = fmaf(g3.y, w3, acc.y);
  }
  for (; i < r1; ++i) {
    const int s = csr_src[i];
    const float w = dinv[s] * dv;
    const float2 g = h2[(size_t)s * 20 + cp];
    acc.x = fmaf(g.x, w, acc.x);
    acc.y = fmaf(g.y, w, acc.y);
  }
  const float2 bv = ((const float2*)bias)[cp];
  float2 v;
  v.x = fmaxf(acc.x + bv.x, 0.f);  // ReLU (layer 1 only)
  v.y = fmaxf(acc.y + bv.y, 0.f);
  ((float2*)out)[(size_t)node * 20 + cp] = v;
}

// Layer 2 (CH=20): float2 packing — 10 lanes/node, 6 nodes/wave.
__global__ __launch_bounds__(256) void k_agg20(const float* __restrict__ h, const int* __restrict__ rowptr,
                                               const int* __restrict__ csr_src, const float* __restrict__ dinv,
                                               const float* __restrict__ bias, float* __restrict__ out, int n) {
  const int wave = (blockIdx.x * 256 + (int)threadIdx.x) >> 6;
  const int lane = threadIdx.x & 63;
  const int sub  = lane / 10;   // 0..5 active; 6 => idle lanes 60..63
  const int cp   = lane % 10;   // channel pair: channels {2cp, 2cp+1}
  const int node = wave * 6 + sub;
  if (sub >= 6 || node >= n) return;
  const float2* __restrict__ h2 = (const float2*)h;
  const int r0 = rowptr[node];
  const int r1 = rowptr[node + 1];
  const float dv = dinv[node];
  const float self_w = dv * dv;
  float2 acc = h2[(size_t)node * 10 + cp];
  acc.x *= self_w;
  acc.y *= self_w;
  int i = r0;
  for (; i + 4 <= r1; i += 4) {
    const int s0 = csr_src[i + 0];
    const int s1 = csr_src[i + 1];
    const int s2 = csr_src[i + 2];
    const int s3 = csr_src[i + 3];
    const float w0 = dinv[s0] * dv;
    const float w1 = dinv[s1] * dv;
    const float w2 = dinv[s2] * dv;
    const float w3 = dinv[s3] * dv;
    const float2 g0 = h2[(size_t)s0 * 10 + cp];
    const float2 g1 = h2[(size_t)s1 * 10 + cp];
    const float2 g2 = h2[(size_t)s2 * 10 + cp];
    const float2 g3 = h2[(size_t)s3 * 10 + cp];
    acc.x = fmaf(g0.x, w0, acc.x); acc.y = fmaf(g0.y, w0, acc.y);
    acc.x = fmaf(g1.x, w1, acc.x); acc.y = fmaf(g1.y, w1, acc.y);
    acc.x = fmaf(g2.x, w2, acc.x); acc.y = fmaf(g2.y, w2, acc.y);
    acc.x = fmaf(g3.x, w3, acc.x); acc.y = fmaf(g3.y, w3, acc.y);
  }
  for (; i < r1; ++i) {
    const int s = csr_src[i];
    const float w = dinv[s] * dv;
    const float2 g = h2[(size_t)s * 10 + cp];
    acc.x = fmaf(g.x, w, acc.x);
    acc.y = fmaf(g.y, w, acc.y);
  }
  const float2 bv = ((const float2*)bias)[cp];
  float2 v;
  v.x = acc.x + bv.x;
  v.y = acc.y + bv.y;
  ((float2*)out)[(size_t)node * 10 + cp] = v;
}

// ---------------- launch ----------------

extern "C" void kernel_launch(void* const* d_in, const int* in_sizes, int n_in,
                              void* d_out, int out_size, void* d_ws, size_t ws_size,
                              hipStream_t stream) {
  const float* x   = (const float*)d_in[0];
  const int*   ei  = (const int*)d_in[1];
  const float* W1  = (const float*)d_in[2];
  const float* b1  = (const float*)d_in[3];
  const float* W2  = (const float*)d_in[4];
  const float* b2  = (const float*)d_in[5];
  float* out = (float*)d_out;

  const int* srcp = ei;        // edge_index[0]
  const int* dstp = ei + NE;   // edge_index[1]

  // workspace layout (~59 MB)
  char* ws = (char*)d_ws;
  size_t off = 0;
  auto take = [&](size_t bytes) -> char* {
    char* p = ws + off;
    off = (off + bytes + 255) & ~(size_t)255;
    return p;
  };
  int*   cnt     = (int*)take((size_t)NN * 4);
  int*   rowptr  = (int*)take((size_t)(NN + 1) * 4);
  float* dinv    = (float*)take((size_t)NN * 4);
  int*   bsums   = (int*)take(256 * 4);
  int*   rank    = (int*)take((size_t)NE * 4);
  int*   csr_src = (int*)take((size_t)NE * 4);
  float* h1      = (float*)take((size_t)NN * CHID * 4);
  float* t1      = (float*)take((size_t)NN * CHID * 4);
  float* g2      = h1;  // h1 dead after agg1; reuse for layer-2 GEMM output

  (void)in_sizes; (void)n_in; (void)out_size; (void)ws_size;

  hipMemsetAsync(cnt, 0, (size_t)NN * 4, stream);

  const int ne4 = NE / 4;  // 800000
  k_count<<<(ne4 + 255) / 256, 256, 0, stream>>>(dstp, cnt, rank, ne4);
  const int nb = (NN + 1023) / 1024;  // 98
  k_scanA<<<nb, 256, 0, stream>>>(cnt, rowptr, bsums, dinv, NN);
  k_scanB<<<1, 256, 0, stream>>>(bsums, nb);
  k_scanC<<<(NN + 255) / 256, 256, 0, stream>>>(rowptr, bsums, NN, NE);
  k_fill<<<(ne4 + 255) / 256, 256, 0, stream>>>(srcp, dstp, rank, rowptr, csr_src, ne4);

  k_gemm1<<<(NN + 63) / 64, 256, 0, stream>>>(x, W1, h1, NN);
  const int nwaves1 = (NN + 2) / 3;            // 3 nodes per wave
  k_agg40<<<(nwaves1 + 3) / 4, 256, 0, stream>>>(h1, rowptr, csr_src, dinv, b1, t1, NN);
  k_gemm2<<<(NN + 255) / 256, 256, 0, stream>>>(t1, W2, g2, NN);
  const int nwaves2 = (NN + 5) / 6;            // 6 nodes per wave
  k_agg20<<<(nwaves2 + 3) / 4, 256, 0, stream>>>(g2, rowptr, csr_src, dinv, b2, out, NN);
}

// Round 11
// 764.091 us; speedup vs baseline: 1.2113x; 1.0796x over previous
//
#include <hip/hip_runtime.h>
#include <cstddef>

// Problem constants (from reference setup_inputs)
static constexpr int NN   = 100000;   // nodes
static constexpr int NE   = 3200000;  // edges
static constexpr int CIN  = 512;
static constexpr int CHID = 40;
static constexpr int COUT = 20;

// clang native vector type: required by __builtin_nontemporal_load
// (HIP float4 is a class type and is rejected -- R9 compile error).
typedef float f32x4 __attribute__((ext_vector_type(4)));

// ---------------- CSR build ----------------

// count in-degree AND record each edge's rank within its dst bucket.
// int4-vectorized: 4 edges/thread -> 4 independent atomics in flight.
__global__ __launch_bounds__(256) void k_count(const int* __restrict__ dst, int* __restrict__ cnt,
                                               int* __restrict__ rank, int n_edges4) {
  const int e4 = blockIdx.x * 256 + threadIdx.x;
  if (e4 >= n_edges4) return;
  const int4 d = ((const int4*)dst)[e4];
  int4 r;
  r.x = atomicAdd(&cnt[d.x], 1);
  r.y = atomicAdd(&cnt[d.y], 1);
  r.z = atomicAdd(&cnt[d.z], 1);
  r.w = atomicAdd(&cnt[d.w], 1);
  ((int4*)rank)[e4] = r;
}

// block of 256 scans 1024 elements; writes per-element exclusive scan (within block),
// block totals, and fused dinv = rsqrt(deg) = rsqrt(cnt+1).
__global__ __launch_bounds__(256) void k_scanA(const int* __restrict__ cnt, int* __restrict__ excl,
                                               int* __restrict__ bsums, float* __restrict__ dinv, int n) {
  __shared__ int sdata[256];
  const int t = threadIdx.x;
  const int base = blockIdx.x * 1024 + t * 4;
  int v[4];
#pragma unroll
  for (int j = 0; j < 4; ++j) {
    const int i = base + j;
    v[j] = (i < n) ? cnt[i] : 0;
    if (i < n) dinv[i] = rsqrtf((float)(v[j] + 1));
  }
  const int s4 = v[0] + v[1] + v[2] + v[3];
  sdata[t] = s4;
  __syncthreads();
  for (int off = 1; off < 256; off <<= 1) {
    int val = 0;
    if (t >= off) val = sdata[t - off];
    __syncthreads();
    sdata[t] += val;
    __syncthreads();
  }
  int run = sdata[t] - s4;  // exclusive prefix of this thread's 4 items
#pragma unroll
  for (int j = 0; j < 4; ++j) {
    const int i = base + j;
    if (i < n) excl[i] = run;
    run += v[j];
  }
  if (t == 255) bsums[blockIdx.x] = sdata[255];
}

__global__ __launch_bounds__(256) void k_scanB(int* __restrict__ bsums, int nb) {
  __shared__ int sdata[256];
  const int t = threadIdx.x;
  const int v = (t < nb) ? bsums[t] : 0;
  sdata[t] = v;
  __syncthreads();
  for (int off = 1; off < 256; off <<= 1) {
    int val = 0;
    if (t >= off) val = sdata[t - off];
    __syncthreads();
    sdata[t] += val;
    __syncthreads();
  }
  if (t < nb) bsums[t] = sdata[t] - v;  // exclusive, in place
}

__global__ __launch_bounds__(256) void k_scanC(int* __restrict__ rowptr, const int* __restrict__ boff,
                                               int n, int n_edges) {
  const int i = blockIdx.x * 256 + threadIdx.x;
  if (i < n) rowptr[i] += boff[i >> 10];
  if (i == 0) rowptr[n] = n_edges;
}

// pure gather + scattered 4B writes (no atomics). int4-vectorized.
__global__ __launch_bounds__(256) void k_fill(const int* __restrict__ src, const int* __restrict__ dst,
                                              const int* __restrict__ rank, const int* __restrict__ rowptr,
                                              int* __restrict__ csr_src, int n_edges4) {
  const int e4 = blockIdx.x * 256 + threadIdx.x;
  if (e4 >= n_edges4) return;
  const int4 s = ((const int4*)src)[e4];
  const int4 d = ((const int4*)dst)[e4];
  const int4 r = ((const int4*)rank)[e4];
  csr_src[rowptr[d.x] + r.x] = s.x;
  csr_src[rowptr[d.y] + r.y] = s.y;
  csr_src[rowptr[d.z] + r.z] = s.z;
  csr_src[rowptr[d.w] + r.w] = s.w;
}

// ---------------- GEMM 1: R7-measured geometry + NT staging loads ----------------
// R10 post-mortem: the 32-node restructure used readfirstlane(t>>5) -- NOT
// wave-uniform on wave64 (lanes 0..31 vs 32..63 differ) -> half the channel
// groups computed wrong. REVERTED to the measured-good R7 kernel (228us,
// absmax 4.88e-4): 64-node tiles, 4 waves, g = t>>6 (genuinely wave-uniform).
// Single variable added vs R7: staging loads are now __builtin_nontemporal_load
// (clang f32x4). Theory: WRITE_SIZE 215.6MB ~= x(204.8) + h(15.6) -- the
// read-once x stream generates L2 victim writebacks; NT no-allocate kills them.
// A/B discriminator: WRITE_SIZE 215.6 -> ~16 MB. Arithmetic bit-identical.
__global__ __launch_bounds__(256) void k_gemm1(const float* __restrict__ x, const float* __restrict__ W,
                                               float* __restrict__ h, int n) {
  __shared__ float xt[64 * 128];  // 32 KB; reused as output staging [64][44]
  const int t  = threadIdx.x;
  const int nd = t & 63;                                   // node-in-tile (compute)
  const int g  = __builtin_amdgcn_readfirstlane(t >> 6);   // channel group 0..3 (wave-uniform)
  const int block0 = blockIdx.x * 64;

  // staging map: idx = r*256 + t -> row = idx>>5, float4-col = idx&31
  const int sn = t >> 5;   // rows sn, sn+8, ..., sn+56
  const int c4 = t & 31;

  float acc[10];
#pragma unroll
  for (int j = 0; j < 10; ++j) acc[j] = 0.f;

  for (int kt = 0; kt < 4; ++kt) {
    // ---- issue coalesced NT staging loads (before barrier: overlap other waves)
    f32x4 v[8];
#pragma unroll
    for (int r = 0; r < 8; ++r) {
      const int row = r * 8 + sn;
      int gn = block0 + row;
      if (gn >= n) gn = n - 1;  // clamp: valid memory, store is guarded
      v[r] = __builtin_nontemporal_load(
          ((const f32x4*)(x + (size_t)gn * CIN + kt * 128)) + c4);
    }
    if (kt) __syncthreads();  // previous tile fully consumed
#pragma unroll
    for (int r = 0; r < 8; ++r) {
      const int row = r * 8 + sn;
      const int byte = row * 512 + ((c4 * 16) ^ ((row & 31) << 4));
      *(f32x4*)((char*)xt + byte) = v[r];
    }
    __syncthreads();          // tile ready

    // ---- compute: 128 k-values, 10 channels per thread
    const float* __restrict__ Wg = W + (size_t)kt * 128 * CHID + g * 10;
#pragma unroll 4
    for (int k4 = 0; k4 < 32; ++k4) {
      const int byte = nd * 512 + ((k4 * 16) ^ ((nd & 31) << 4));
      const f32x4 xv = *(const f32x4*)((const char*)xt + byte);
      const float* __restrict__ Wk = Wg + k4 * 4 * CHID;
#pragma unroll
      for (int j = 0; j < 10; ++j) acc[j] = fmaf(xv.x, Wk[j], acc[j]);
#pragma unroll
      for (int j = 0; j < 10; ++j) acc[j] = fmaf(xv.y, Wk[CHID + j], acc[j]);
#pragma unroll
      for (int j = 0; j < 10; ++j) acc[j] = fmaf(xv.z, Wk[2 * CHID + j], acc[j]);
#pragma unroll
      for (int j = 0; j < 10; ++j) acc[j] = fmaf(xv.w, Wk[3 * CHID + j], acc[j]);
    }
  }

  // ---- coalesced epilogue through LDS ----
  __syncthreads();  // all waves done reading xt
#pragma unroll
  for (int j = 0; j < 10; ++j) xt[nd * 44 + g * 10 + j] = acc[j];
  __syncthreads();
  // 64 rows x 40 floats = 640 float4, contiguous across the block's h region
  for (int i = t; i < 640; i += 256) {
    const int row = i / 10;
    const int c   = i % 10;
    const int node = block0 + row;
    if (node < n)
      ((float4*)(h + (size_t)node * CHID))[c] = *(const float4*)&xt[row * 44 + c * 4];
  }
}

__global__ __launch_bounds__(256) void k_gemm2(const float* __restrict__ t1, const float* __restrict__ W,
                                               float* __restrict__ g, int n) {
  const int node = blockIdx.x * 256 + threadIdx.x;
  if (node >= n) return;
  const float4* __restrict__ r4 = (const float4*)(t1 + (size_t)node * CHID);
  float acc[COUT];
#pragma unroll
  for (int c = 0; c < COUT; ++c) acc[c] = 0.f;
#pragma unroll
  for (int kk = 0; kk < CHID / 4; ++kk) {
    const float4 xv = r4[kk];
    const float* __restrict__ Wk = W + kk * 4 * COUT;
#pragma unroll
    for (int c = 0; c < COUT; ++c) {
      float a = acc[c];
      a = fmaf(xv.x, Wk[c], a);
      a = fmaf(xv.y, Wk[COUT + c], a);
      a = fmaf(xv.z, Wk[2 * COUT + c], a);
      a = fmaf(xv.w, Wk[3 * COUT + c], a);
      acc[c] = a;
    }
  }
  float* __restrict__ o = g + (size_t)node * COUT;
#pragma unroll
  for (int c = 0; c < COUT; ++c) o[c] = acc[c];
}

// ---------------- CSR aggregation ----------------
// Layer 1 (CH=40): float2 channel-packing — 20 lanes/node, 3 nodes/wave.
__global__ __launch_bounds__(256) void k_agg40(const float* __restrict__ h, const int* __restrict__ rowptr,
                                               const int* __restrict__ csr_src, const float* __restrict__ dinv,
                                               const float* __restrict__ bias, float* __restrict__ out, int n) {
  const int wave = (blockIdx.x * 256 + (int)threadIdx.x) >> 6;
  const int lane = threadIdx.x & 63;
  const int sub  = lane / 20;   // 0..2 active; 3 => idle lanes 60..63
  const int cp   = lane % 20;   // channel pair: channels {2cp, 2cp+1}
  const int node = wave * 3 + sub;
  if (sub >= 3 || node >= n) return;
  const float2* __restrict__ h2 = (const float2*)h;
  const int r0 = rowptr[node];
  const int r1 = rowptr[node + 1];
  const float dv = dinv[node];
  const float self_w = dv * dv;  // self-loop norm = 1/deg
  float2 acc = h2[(size_t)node * 20 + cp];
  acc.x *= self_w;
  acc.y *= self_w;
  int i = r0;
  for (; i + 4 <= r1; i += 4) {
    const int s0 = csr_src[i + 0];
    const int s1 = csr_src[i + 1];
    const int s2 = csr_src[i + 2];
    const int s3 = csr_src[i + 3];
    const float w0 = dinv[s0] * dv;
    const float w1 = dinv[s1] * dv;
    const float w2 = dinv[s2] * dv;
    const float w3 = dinv[s3] * dv;
    const float2 g0 = h2[(size_t)s0 * 20 + cp];
    const float2 g1 = h2[(size_t)s1 * 20 + cp];
    const float2 g2 = h2[(size_t)s2 * 20 + cp];
    const float2 g3 = h2[(size_t)s3 * 20 + cp];
    acc.x = fmaf(g0.x, w0, acc.x); acc.y = fmaf(g0.y, w0, acc.y);
    acc.x = fmaf(g1.x, w1, acc.x); acc.y = fmaf(g1.y, w1, acc.y);
    acc.x = fmaf(g2.x, w2, acc.x); acc.y = fmaf(g2.y, w2, acc.y);
    acc.x = fmaf(g3.x, w3, acc.x); acc.y = fmaf(g3.y, w3, acc.y);
  }
  for (; i < r1; ++i) {
    const int s = csr_src[i];
    const float w = dinv[s] * dv;
    const float2 g = h2[(size_t)s * 20 + cp];
    acc.x = fmaf(g.x, w, acc.x);
    acc.y = fmaf(g.y, w, acc.y);
  }
  const float2 bv = ((const float2*)bias)[cp];
  float2 v;
  v.x = fmaxf(acc.x + bv.x, 0.f);  // ReLU (layer 1 only)
  v.y = fmaxf(acc.y + bv.y, 0.f);
  ((float2*)out)[(size_t)node * 20 + cp] = v;
}

// Layer 2 (CH=20): float2 packing — 10 lanes/node, 6 nodes/wave.
__global__ __launch_bounds__(256) void k_agg20(const float* __restrict__ h, const int* __restrict__ rowptr,
                                               const int* __restrict__ csr_src, const float* __restrict__ dinv,
                                               const float* __restrict__ bias, float* __restrict__ out, int n) {
  const int wave = (blockIdx.x * 256 + (int)threadIdx.x) >> 6;
  const int lane = threadIdx.x & 63;
  const int sub  = lane / 10;   // 0..5 active; 6 => idle lanes 60..63
  const int cp   = lane % 10;   // channel pair: channels {2cp, 2cp+1}
  const int node = wave * 6 + sub;
  if (sub >= 6 || node >= n) return;
  const float2* __restrict__ h2 = (const float2*)h;
  const int r0 = rowptr[node];
  const int r1 = rowptr[node + 1];
  const float dv = dinv[node];
  const float self_w = dv * dv;
  float2 acc = h2[(size_t)node * 10 + cp];
  acc.x *= self_w;
  acc.y *= self_w;
  int i = r0;
  for (; i + 4 <= r1; i += 4) {
    const int s0 = csr_src[i + 0];
    const int s1 = csr_src[i + 1];
    const int s2 = csr_src[i + 2];
    const int s3 = csr_src[i + 3];
    const float w0 = dinv[s0] * dv;
    const float w1 = dinv[s1] * dv;
    const float w2 = dinv[s2] * dv;
    const float w3 = dinv[s3] * dv;
    const float2 g0 = h2[(size_t)s0 * 10 + cp];
    const float2 g1 = h2[(size_t)s1 * 10 + cp];
    const float2 g2 = h2[(size_t)s2 * 10 + cp];
    const float2 g3 = h2[(size_t)s3 * 10 + cp];
    acc.x = fmaf(g0.x, w0, acc.x); acc.y = fmaf(g0.y, w0, acc.y);
    acc.x = fmaf(g1.x, w1, acc.x); acc.y = fmaf(g1.y, w1, acc.y);
    acc.x = fmaf(g2.x, w2, acc.x); acc.y = fmaf(g2.y, w2, acc.y);
    acc.x = fmaf(g3.x, w3, acc.x); acc.y = fmaf(g3.y, w3, acc.y);
  }
  for (; i < r1; ++i) {
    const int s = csr_src[i];
    const float w = dinv[s] * dv;
    const float2 g = h2[(size_t)s * 10 + cp];
    acc.x = fmaf(g.x, w, acc.x);
    acc.y = fmaf(g.y, w, acc.y);
  }
  const float2 bv = ((const float2*)bias)[cp];
  float2 v;
  v.x = acc.x + bv.x;
  v.y = acc.y + bv.y;
  ((float2*)out)[(size_t)node * 10 + cp] = v;
}

// ---------------- launch ----------------

extern "C" void kernel_launch(void* const* d_in, const int* in_sizes, int n_in,
                              void* d_out, int out_size, void* d_ws, size_t ws_size,
                              hipStream_t stream) {
  const float* x   = (const float*)d_in[0];
  const int*   ei  = (const int*)d_in[1];
  const float* W1  = (const float*)d_in[2];
  const float* b1  = (const float*)d_in[3];
  const float* W2  = (const float*)d_in[4];
  const float* b2  = (const float*)d_in[5];
  float* out = (float*)d_out;

  const int* srcp = ei;        // edge_index[0]
  const int* dstp = ei + NE;   // edge_index[1]

  // workspace layout (~59 MB)
  char* ws = (char*)d_ws;
  size_t off = 0;
  auto take = [&](size_t bytes) -> char* {
    char* p = ws + off;
    off = (off + bytes + 255) & ~(size_t)255;
    return p;
  };
  int*   cnt     = (int*)take((size_t)NN * 4);
  int*   rowptr  = (int*)take((size_t)(NN + 1) * 4);
  float* dinv    = (float*)take((size_t)NN * 4);
  int*   bsums   = (int*)take(256 * 4);
  int*   rank    = (int*)take((size_t)NE * 4);
  int*   csr_src = (int*)take((size_t)NE * 4);
  float* h1      = (float*)take((size_t)NN * CHID * 4);
  float* t1      = (float*)take((size_t)NN * CHID * 4);
  float* g2      = h1;  // h1 dead after agg1; reuse for layer-2 GEMM output

  (void)in_sizes; (void)n_in; (void)out_size; (void)ws_size;

  hipMemsetAsync(cnt, 0, (size_t)NN * 4, stream);

  const int ne4 = NE / 4;  // 800000
  k_count<<<(ne4 + 255) / 256, 256, 0, stream>>>(dstp, cnt, rank, ne4);
  const int nb = (NN + 1023) / 1024;  // 98
  k_scanA<<<nb, 256, 0, stream>>>(cnt, rowptr, bsums, dinv, NN);
  k_scanB<<<1, 256, 0, stream>>>(bsums, nb);
  k_scanC<<<(NN + 255) / 256, 256, 0, stream>>>(rowptr, bsums, NN, NE);
  k_fill<<<(ne4 + 255) / 256, 256, 0, stream>>>(srcp, dstp, rank, rowptr, csr_src, ne4);

  k_gemm1<<<(NN + 63) / 64, 256, 0, stream>>>(x, W1, h1, NN);
  const int nwaves1 = (NN + 2) / 3;            // 3 nodes per wave
  k_agg40<<<(nwaves1 + 3) / 4, 256, 0, stream>>>(h1, rowptr, csr_src, dinv, b1, t1, NN);
  k_gemm2<<<(NN + 255) / 256, 256, 0, stream>>>(t1, W2, g2, NN);
  const int nwaves2 = (NN + 5) / 6;            // 6 nodes per wave
  k_agg20<<<(nwaves2 + 3) / 4, 256, 0, stream>>>(g2, rowptr, csr_src, dinv, b2, out, NN);
}